// Round 1
// baseline (165.508 us; speedup 1.0000x reference)
//
#include <hip/hip_runtime.h>
#include <hip/hip_bf16.h>

#define NVIS   16384
#define NTAC   2048
#define NPRED  (NVIS + NTAC)   // 18432
#define NMODEL 8192
#define CHUNK  1024
#define NCHUNK (NMODEL / CHUNK)  // 8
#define BLK    256

// Kernel 1: per-(pred-block, model-chunk) partial min of squared distance.
__global__ __launch_bounds__(BLK) void cd_partial_kernel(
    const float* __restrict__ vis,
    const float* __restrict__ tac,
    const float* __restrict__ model,
    const float* __restrict__ scale,
    const float* __restrict__ state,
    float* __restrict__ mins)           // [NPRED][NCHUNK]
{
    __shared__ float4 sm[CHUNK];

    const int tid   = threadIdx.x;
    const int chunk = blockIdx.y;
    const int mbase = chunk * CHUNK;

    // Stage model chunk into LDS (each thread loads CHUNK/BLK points).
    #pragma unroll
    for (int k = 0; k < CHUNK / BLK; ++k) {
        int j = tid + k * BLK;
        const float* mp = model + 3 * (mbase + j);
        sm[j] = make_float4(mp[0], mp[1], mp[2], 0.0f);
    }

    // Build rotation R = Rz @ Ry @ Rx from state[3:6]; vc[j] = sum_k p[k]*R[k][j].
    const float ax = state[3], ay = state[4], az = state[5];
    const float sx = sinf(ax), cx = cosf(ax);
    const float sy = sinf(ay), cy = cosf(ay);
    const float sz = sinf(az), cz = cosf(az);
    const float R00 = cz * cy;
    const float R01 = cz * sy * sx - sz * cx;
    const float R02 = cz * sy * cx + sz * sx;
    const float R10 = sz * cy;
    const float R11 = sz * sy * sx + cz * cx;
    const float R12 = sz * sy * cx - cz * sx;
    const float R20 = -sy;
    const float R21 = cy * sx;
    const float R22 = cy * cx;

    const float inv = 1.0f / scale[0];
    const float t0 = state[0], t1 = state[1], t2 = state[2];

    const int pid = blockIdx.x * BLK + tid;   // grid sized exactly: 72*256 = 18432
    const float* pp = (pid < NVIS) ? (vis + 3 * pid) : (tac + 3 * (pid - NVIS));
    const float p0 = pp[0] - t0;
    const float p1 = pp[1] - t1;
    const float p2 = pp[2] - t2;
    // (p-t) @ R  (row-vector times matrix: dot with R columns)
    const float vx = (p0 * R00 + p1 * R10 + p2 * R20) * inv;
    const float vy = (p0 * R01 + p1 * R11 + p2 * R21) * inv;
    const float vz = (p0 * R02 + p1 * R12 + p2 * R22) * inv;

    __syncthreads();

    float best = 3.4e38f;
    #pragma unroll 8
    for (int j = 0; j < CHUNK; ++j) {
        float4 m = sm[j];                 // wave-uniform address -> LDS broadcast
        float d0 = vx - m.x;
        float d1 = vy - m.y;
        float d2 = vz - m.z;
        float d = fmaf(d0, d0, fmaf(d1, d1, d2 * d2));
        best = fminf(best, d);
    }

    mins[pid * NCHUNK + chunk] = best;
}

// Kernel 2: combine chunk mins, weighted mean -> E.
__global__ __launch_bounds__(1024) void cd_reduce_kernel(
    const float* __restrict__ mins,     // [NPRED][NCHUNK]
    float* __restrict__ out)
{
    __shared__ float svis[1024];
    __shared__ float stac[1024];

    const int tid = threadIdx.x;
    float vs = 0.0f, ts = 0.0f;

    for (int i = tid; i < NPRED; i += 1024) {
        const float* m = mins + i * NCHUNK;
        float b = m[0];
        #pragma unroll
        for (int k = 1; k < NCHUNK; ++k) b = fminf(b, m[k]);
        if (i < NVIS) vs += b; else ts += b;
    }

    svis[tid] = vs;
    stac[tid] = ts;
    __syncthreads();

    #pragma unroll
    for (int s = 512; s > 0; s >>= 1) {
        if (tid < s) {
            svis[tid] += svis[tid + s];
            stac[tid] += stac[tid + s];
        }
        __syncthreads();
    }

    if (tid == 0) {
        out[0] = svis[0] / (float)NVIS + 0.1f * (stac[0] / (float)NTAC);
    }
}

extern "C" void kernel_launch(void* const* d_in, const int* in_sizes, int n_in,
                              void* d_out, int out_size, void* d_ws, size_t ws_size,
                              hipStream_t stream) {
    const float* vis   = (const float*)d_in[0];
    const float* tac   = (const float*)d_in[1];
    const float* model = (const float*)d_in[2];
    const float* scale = (const float*)d_in[3];
    const float* state = (const float*)d_in[4];
    float* out  = (float*)d_out;
    float* mins = (float*)d_ws;          // NPRED * NCHUNK floats = 576 KB

    dim3 grid(NPRED / BLK, NCHUNK);      // (72, 8)
    cd_partial_kernel<<<grid, BLK, 0, stream>>>(vis, tac, model, scale, state, mins);
    cd_reduce_kernel<<<1, 1024, 0, stream>>>(mins, out);
}

// Round 2
// 78.690 us; speedup vs baseline: 2.1033x; 2.1033x over previous
//
#include <hip/hip_runtime.h>
#include <hip/hip_bf16.h>

#define NVIS   16384
#define NTAC   2048
#define NPRED  (NVIS + NTAC)     // 18432
#define NMODEL 8192

#define BLK    256
#define PPT    3                 // pred points per thread
#define TILE   (BLK * PPT)       // 768 pred points per block
#define NTILE  (NPRED / TILE)    // 24
#define CHUNK  256               // model points per block
#define NCHUNK (NMODEL / CHUNK)  // 32
// grid = 24 x 32 = 768 blocks = exactly 3 blocks per CU (256 CUs)

#define BIGF   3.4e38f

// Kernel 1: per-(pred-tile, model-chunk) partial min.
// Uses dist = |p|^2 + |m|^2 - 2 p.m ; stages q = 0.5|m|^2 in LDS w-component,
// computes s = q - p.m (3 fma + 1 fmin per pair), stores |p|^2 + 2*min(s).
__global__ __launch_bounds__(BLK) void cd_partial_kernel(
    const float* __restrict__ vis,
    const float* __restrict__ tac,
    const float* __restrict__ model,
    const float* __restrict__ scale,
    const float* __restrict__ state,
    float* __restrict__ mins)           // [NCHUNK][NPRED], transposed
{
    __shared__ float4 sm[CHUNK];

    const int tid   = threadIdx.x;
    const int tile  = blockIdx.x;
    const int chunk = blockIdx.y;

    // --- stage model chunk (one point per thread), fold 0.5*|m|^2 into w ---
    {
        const float* mp = model + 3 * (chunk * CHUNK + tid);
        float mx = mp[0], my = mp[1], mz = mp[2];
        float q = 0.5f * (mx * mx + my * my + mz * mz);
        sm[tid] = make_float4(mx, my, mz, q);
    }

    // --- rotation R = Rz @ Ry @ Rx from state[3:6] ---
    const float ax = state[3], ay = state[4], az = state[5];
    const float sx = sinf(ax), cx = cosf(ax);
    const float sy = sinf(ay), cy = cosf(ay);
    const float sz = sinf(az), cz = cosf(az);
    const float R00 = cz * cy;
    const float R01 = cz * sy * sx - sz * cx;
    const float R02 = cz * sy * cx + sz * sx;
    const float R10 = sz * cy;
    const float R11 = sz * sy * sx + cz * cx;
    const float R12 = sz * sy * cx - cz * sx;
    const float R20 = -sy;
    const float R21 = cy * sx;
    const float R22 = cy * cx;

    const float inv = 1.0f / scale[0];
    const float t0 = state[0], t1 = state[1], t2 = state[2];

    // --- load + transform PPT pred points (coalesced: tid, tid+256, tid+512) ---
    float nx[PPT], ny[PPT], nz[PPT], pa[PPT];
    #pragma unroll
    for (int k = 0; k < PPT; ++k) {
        int pid = tile * TILE + k * BLK + tid;
        const float* pp = (pid < NVIS) ? (vis + 3 * pid) : (tac + 3 * (pid - NVIS));
        float p0 = pp[0] - t0;
        float p1 = pp[1] - t1;
        float p2 = pp[2] - t2;
        float vx = (p0 * R00 + p1 * R10 + p2 * R20) * inv;
        float vy = (p0 * R01 + p1 * R11 + p2 * R21) * inv;
        float vz = (p0 * R02 + p1 * R12 + p2 * R22) * inv;
        pa[k] = vx * vx + vy * vy + vz * vz;
        nx[k] = -vx; ny[k] = -vy; nz[k] = -vz;   // negate once: inner is pure fma
    }

    __syncthreads();

    float b0 = BIGF, b1 = BIGF, b2 = BIGF;
    #pragma unroll 8
    for (int j = 0; j < CHUNK; ++j) {
        float4 m = sm[j];      // wave-uniform address -> LDS broadcast
        b0 = fminf(b0, fmaf(nx[0], m.x, fmaf(ny[0], m.y, fmaf(nz[0], m.z, m.w))));
        b1 = fminf(b1, fmaf(nx[1], m.x, fmaf(ny[1], m.y, fmaf(nz[1], m.z, m.w))));
        b2 = fminf(b2, fmaf(nx[2], m.x, fmaf(ny[2], m.y, fmaf(nz[2], m.z, m.w))));
    }

    // store pa + 2*best (monotone per point: cross-chunk min still works)
    float* mrow = mins + (size_t)chunk * NPRED + tile * TILE + tid;
    mrow[0 * BLK] = fmaf(2.0f, b0, pa[0]);
    mrow[1 * BLK] = fmaf(2.0f, b1, pa[1]);
    mrow[2 * BLK] = fmaf(2.0f, b2, pa[2]);
}

// Kernel 2: min over chunks per point, block-sum, weighted atomicAdd -> E.
// Blocks 0..63 cover visual (64*256=16384), blocks 64..71 cover tactile.
__global__ __launch_bounds__(BLK) void cd_reduce_kernel(
    const float* __restrict__ mins,     // [NCHUNK][NPRED]
    float* __restrict__ out)
{
    const int tid = threadIdx.x;
    const int pid = blockIdx.x * BLK + tid;

    float b = mins[pid];
    #pragma unroll
    for (int c = 1; c < NCHUNK; ++c)
        b = fminf(b, mins[(size_t)c * NPRED + pid]);

    // wave reduce (64 lanes)
    float v = b;
    #pragma unroll
    for (int off = 32; off > 0; off >>= 1)
        v += __shfl_down(v, off, 64);

    __shared__ float s[BLK / 64];
    if ((tid & 63) == 0) s[tid >> 6] = v;
    __syncthreads();

    if (tid == 0) {
        float t = s[0] + s[1] + s[2] + s[3];
        float scaled = (blockIdx.x < NVIS / BLK) ? t * (1.0f / (float)NVIS)
                                                 : t * (0.1f / (float)NTAC);
        atomicAdd(out, scaled);
    }
}

extern "C" void kernel_launch(void* const* d_in, const int* in_sizes, int n_in,
                              void* d_out, int out_size, void* d_ws, size_t ws_size,
                              hipStream_t stream) {
    const float* vis   = (const float*)d_in[0];
    const float* tac   = (const float*)d_in[1];
    const float* model = (const float*)d_in[2];
    const float* scale = (const float*)d_in[3];
    const float* state = (const float*)d_in[4];
    float* out  = (float*)d_out;
    float* mins = (float*)d_ws;          // NCHUNK * NPRED floats = 2.36 MB

    hipMemsetAsync(out, 0, sizeof(float), stream);   // out is re-poisoned each call

    dim3 grid(NTILE, NCHUNK);            // (24, 32) = 768 blocks = 3/CU
    cd_partial_kernel<<<grid, BLK, 0, stream>>>(vis, tac, model, scale, state, mins);
    cd_reduce_kernel<<<NPRED / BLK, BLK, 0, stream>>>(mins, out);
}